// Round 15
// baseline (182.748 us; speedup 1.0000x reference)
//
#include <hip/hip_runtime.h>
#include <hip/hip_bf16.h>

typedef unsigned short u16;
typedef unsigned int   u32;
typedef __attribute__((ext_vector_type(8))) short s16x8;
typedef __attribute__((ext_vector_type(16))) float f32x16;

#define BN_EPS 1e-3f
// problem dims
#define NB 16
#define NC 64
#define NH 160
#define NW 160
#define HP 162   // padded H
#define WPD 162  // padded W

// workspace layout (bytes)
#define OFF_XT 0UL
#define SZ_XT  (16UL*162*162*64*2)     // 53,747,712  padded NHWC bf16
#define OFF_WT (OFF_XT + SZ_XT)
#define SZ_WT  (4UL*64*9*64*2)         // 294,912  [stage][pos][kh][co][8ci] bf16
#define OFF_SH (OFF_WT + SZ_WT)        // bn shift [4][64] f32
#define OFF_G  (OFF_SH + 1024UL)       // g [16][64] f32
#define OFF_WE (OFF_G + 4096UL)        // wexp [16][4] f32
#define OFF_GP (OFF_WE + 256UL)        // gpart [1024][800] f32 (3.28 MB)

// conv_main LDS partition (dynamic, 81,664 B total -> 2 blocks/CU)
#define XSTRIDE 342
#define XLS_BYTES (8 * XSTRIDE * 16)   // 43,776
#define WLS_BYTES (2 * 1152 * 16)      // 36,864 = 2 buffers x 18 rows x 64 co x 16 B
#define SHLS_BYTES 1024                // shift [4][64] f32 in LDS
#define SMEM_TOTAL (XLS_BYTES + WLS_BYTES + SHLS_BYTES)

__device__ __forceinline__ u16 f2bf(float f) {
    u32 u = __builtin_bit_cast(u32, f);
    u += 0x7fffu + ((u >> 16) & 1u);   // round-to-nearest-even
    return (u16)(u >> 16);
}

// ---- weights -> [stage s=e*4+ch*2+ks][pos][kh][co][8ci] bf16 --------------
// stage panel = one linear 18,432 B chunk; pos stores tap (p%3)*3+(p/3)
// (dx-major); BN scale folded in: w' = w * gamma*rsqrt(var+eps).
__global__ void prep_w(const float* __restrict__ cw, u16* __restrict__ wt,
                       const float* __restrict__ gamma, const float* __restrict__ beta,
                       const float* __restrict__ mean, const float* __restrict__ var,
                       float* __restrict__ shift) {
    int idx = blockIdx.x * 256 + threadIdx.x;
    if (idx < 16 * 9 * 2 * 64 * 8) {
        int cin = idx & 7;
        int o = idx >> 3;
        int co = o & 63; o >>= 6;
        int kh = o & 1;  o >>= 1;
        int pos = o % 9; o /= 9;
        int s = o;                       // stage 0..15
        int ks = s & 1, ch = (s >> 1) & 1, e = s >> 2;
        int tsp = (pos % 3) * 3 + (pos / 3);   // spatial tap dy*3+dx
        int ci = ch * 32 + ks * 16 + kh * 8 + cin;
        int ec = e * 64 + co;
        float sc = gamma[ec] * rsqrtf(var[ec] + BN_EPS);
        wt[idx] = f2bf(cw[(((long)ec) * 64 + ci) * 9 + tsp] * sc);
    }
    if (idx < 256) {
        float sc = gamma[idx] * rsqrtf(var[idx] + BN_EPS);
        shift[idx] = beta[idx] - mean[idx] * sc;
    }
}

// ---- x NCHW f32 -> padded NHWC bf16 + router partials + border zero ------
__global__ void prep_x(const float* __restrict__ x, u16* __restrict__ xt,
                       float* __restrict__ gpart) {
    __shared__ float tile[64][33];
    int blk = blockIdx.x;
    int t = threadIdx.x;
    if (blk >= 12800) {                // zero the 1-px halo border
        int bb = blk - 12800;          // 0..2591 = b*162 + hp
        int hp = bb % 162, b = bb / 162;
        u32* row = (u32*)xt + (((long)b * 162 + hp) * 162) * 32;
        if (hp == 0 || hp == 161) {
            for (int i = t; i < 162 * 32; i += 256) row[i] = 0u;
        } else if (t < 64) {
            int p = (t >> 5) ? 161 : 0;
            row[p * 32 + (t & 31)] = 0u;
        }
        return;
    }
    int wt5 = blk % 5;
    int tmp = blk / 5;
    int h = tmp % 160, b = tmp / 160;
    int w0 = wt5 * 32;
    int w = t & 31, c0 = t >> 5;       // c0 in 0..7
#pragma unroll
    for (int i = 0; i < 8; ++i) {
        int c = c0 + 8 * i;
        tile[c][w] = x[(((long)b * 64 + c) * 160 + h) * 160 + w0 + w];
    }
    __syncthreads();
    if (t < 64) {                      // per-channel partial sum over 32 w
        float s = 0.f;
#pragma unroll
        for (int wi = 0; wi < 32; ++wi) s += tile[t][wi];
        gpart[((long)(b * 64 + t)) * 800 + h * 5 + wt5] = s;
    }
    u32* xt32 = (u32*)xt;
    long base = ((((long)b * 162 + h + 1) * 162) + (w0 + 1)) * 32; // u32 index
#pragma unroll
    for (int j = 0; j < 4; ++j) {
        int idx = t + 256 * j;         // 0..1023
        int p = idx >> 5, cp = idx & 31;
        float v0 = tile[2 * cp][p], v1 = tile[2 * cp + 1][p];
        xt32[base + p * 32 + cp] = (u32)f2bf(v0) | ((u32)f2bf(v1) << 16);
    }
}

// ---- finish global average pool (1024 blocks: parallel) ------------------
__global__ void g_reduce(const float* __restrict__ gpart, float* __restrict__ g) {
    int id = blockIdx.x;               // 1024 = b*64+c
    int t = threadIdx.x;
    float s = 0.f;
    for (int i = t; i < 800; i += 256) s += gpart[(long)id * 800 + i];
#pragma unroll
    for (int off = 32; off > 0; off >>= 1) s += __shfl_down(s, off, 64);
    __shared__ float red[4];
    if ((t & 63) == 0) red[t >> 6] = s;
    __syncthreads();
    if (t == 0) g[id] = (red[0] + red[1] + red[2] + red[3]) * (1.f / 25600.f);
}

// ---- router: fc1 -> relu -> fc2 -> softmax -------------------------------
__global__ void router(const float* __restrict__ g, const float* __restrict__ fc1w,
                       const float* __restrict__ fc2w, const float* __restrict__ fc2b,
                       float* __restrict__ wexp) {
    __shared__ float gL[16][64];
    __shared__ float h1[16][16];
    __shared__ float z[16][4];
    int t = threadIdx.x;
    for (int i = t; i < 1024; i += 256) gL[i >> 6][i & 63] = g[i];
    __syncthreads();
    {
        int b = t >> 4, r = t & 15;
        float s = 0.f;
#pragma unroll
        for (int c = 0; c < 64; ++c) s += gL[b][c] * fc1w[r * 64 + c];
        h1[b][r] = fmaxf(s, 0.f);
    }
    __syncthreads();
    if (t < 64) {
        int b = t >> 2, e = t & 3;
        float s = fc2b[e];
#pragma unroll
        for (int r = 0; r < 16; ++r) s += h1[b][r] * fc2w[e * 16 + r];
        z[b][e] = s;
    }
    __syncthreads();
    if (t < 16) {
        int b = t;
        float m = fmaxf(fmaxf(z[b][0], z[b][1]), fmaxf(z[b][2], z[b][3]));
        float e0 = __expf(z[b][0] - m), e1 = __expf(z[b][1] - m);
        float e2 = __expf(z[b][2] - m), e3 = __expf(z[b][3] - m);
        float inv = 1.f / (e0 + e1 + e2 + e3);
        wexp[b * 4 + 0] = e0 * inv; wexp[b * 4 + 1] = e1 * inv;
        wexp[b * 4 + 2] = e2 * inv; wexp[b * 4 + 3] = e3 * inv;
    }
}

// ---- main: 4-expert implicit-GEMM conv + BN + SiLU + weighted sum --------
// grid 1600; block 256 (4 waves). WAVE RETILE: 32co x 128px per wave
// (wv>>1 = co half, wv&1 = row quad). Per stage per wave: 9 A + 18 B
// ds_read_b128 (was 18+12) -> -10% LDS reads, A-redundancy halved.
// Same 16-stage double-buffered DMA pipeline as R14; epilogue VMEM-free.
__global__ __launch_bounds__(256, 2) void conv_main(
    const u16* __restrict__ xt, const u16* __restrict__ wt,
    const float* __restrict__ shift,
    const float* __restrict__ wexp, float* __restrict__ out) {
    extern __shared__ char smem[];
    u16* xls = (u16*)smem;                       // [cg 8][P @342] octets
    u16* wls = (u16*)(smem + XLS_BYTES);         // 2 x [18 rows][64 co] octets
    float* shls = (float*)(smem + XLS_BYTES + WLS_BYTES);   // [4][64] f32

    // bijective chunked XCD swizzle (1600 % 8 == 0)
    const int o = blockIdx.x;
    const int blk = (o & 7) * 200 + (o >> 3);
    const int wt5 = blk % 5;
    const int tmp = blk / 5;
    const int ht = tmp % 20;
    const int b = tmp / 20;
    const int h0 = ht * 8, w0 = wt5 * 32;
    const int tid = threadIdx.x;
    const int lane = tid & 63;
    const int wv = tid >> 6;
    const int l31 = lane & 31, kh = lane >> 5;
    const int half = wv >> 1;                    // co half (0: 0-31, 1: 32-63)
    const int rows4 = (wv & 1) * 4;              // wave's four output rows

    // issue stage-0 weight DMA first (buffer 0): 6 rounds x 192 threads
    if (tid < 192) {
#pragma unroll
        for (int r = 0; r < 6; ++r) {
            int oo = r * 192 + tid;
            __builtin_amdgcn_global_load_lds(
                (const __attribute__((address_space(1))) void*)(wt + oo * 8),
                (__attribute__((address_space(3))) void*)(wls + oo * 8),
                16, 0, 0);
        }
    }
    // preload router weights (4 regs) + shift into LDS (1 KB)
    const float we0 = wexp[(b << 2) + 0];
    const float we1 = wexp[(b << 2) + 1];
    const float we2 = wexp[(b << 2) + 2];
    const float we3 = wexp[(b << 2) + 3];
    shls[tid] = shift[tid];
    // stage x halo tile (rows h0..h0+9, cols w0..w0+33) into [cg][P@342]
    {
        const u16* xb = xt + (long)b * HP * WPD * 64;
        for (int c = tid; c < 2720; c += 256) {
            int P = c >> 3, cg = c & 7;
            int y = P / 34, px = P - y * 34;
            const u16* src = xb + (((long)(h0 + y) * WPD) + (w0 + px)) * 64 + cg * 8;
            s16x8 v = *(const s16x8*)src;
            *(s16x8*)(&xls[(cg * XSTRIDE + P) << 3]) = v;
        }
    }

    // A base (u16 idx): octet [pos][kh][half*32 + l31]; pos step = 1024
    const int oA2 = ((kh * 64) + half * 32 + l31) << 3;

    f32x16 acc0 = (f32x16)(0.f), acc1 = (f32x16)(0.f);
    f32x16 acc2 = (f32x16)(0.f), acc3 = (f32x16)(0.f);
    f32x16 oac0 = (f32x16)(0.f), oac1 = (f32x16)(0.f);
    f32x16 oac2 = (f32x16)(0.f), oac3 = (f32x16)(0.f);

    auto epi = [&](int E) {
        const float we = (E == 0) ? we0 : (E == 1) ? we1 : (E == 2) ? we2 : we3;
        const float* shE = shls + (E << 6) + half * 32;   // LDS broadcast
#pragma unroll
        for (int j = 0; j < 16; ++j) {
            const int cob = (j & 3) + 8 * (j >> 2) + 4 * kh;
            float sh = shE[cob];
            float y0 = acc0[j] + sh;
            float y1 = acc1[j] + sh;
            float y2 = acc2[j] + sh;
            float y3 = acc3[j] + sh;
            oac0[j] += we * (y0 * __builtin_amdgcn_rcpf(1.f + __expf(-y0)));
            oac1[j] += we * (y1 * __builtin_amdgcn_rcpf(1.f + __expf(-y1)));
            oac2[j] += we * (y2 * __builtin_amdgcn_rcpf(1.f + __expf(-y2)));
            oac3[j] += we * (y3 * __builtin_amdgcn_rcpf(1.f + __expf(-y3)));
        }
        acc0 = (f32x16)(0.f); acc1 = (f32x16)(0.f);
        acc2 = (f32x16)(0.f); acc3 = (f32x16)(0.f);
    };

#pragma unroll 1
    for (int s = 0; s < 16; ++s) {
        const int ks = s & 1, ch = (s >> 1) & 1;
        const int wbU = (s & 1) * 9216;          // this stage's buffer (u16 idx)

        // drain THIS stage's DMA (issued one full stage ago), then sync.
        if (s == 0) __builtin_amdgcn_s_waitcnt(0x070);   // vmcnt(0) lgkmcnt(0)
        else        __builtin_amdgcn_s_waitcnt(0xF70);   // vmcnt(0)
        __builtin_amdgcn_s_barrier();
        __builtin_amdgcn_sched_barrier(0);

        // prefetch next stage into the OTHER buffer
        if (s < 15 && tid < 192) {
            const u16* wsrc = wt + (long)(s + 1) * 9216;
            const int dbU = ((s + 1) & 1) * 9216;
#pragma unroll
            for (int r = 0; r < 6; ++r) {
                int oo = r * 192 + tid;
                __builtin_amdgcn_global_load_lds(
                    (const __attribute__((address_space(1))) void*)(wsrc + oo * 8),
                    (__attribute__((address_space(3))) void*)(wls + dbU + oo * 8),
                    16, 0, 0);
            }
        }

        // B base for this stage: cg = ch*4 + ks*2 + kh; rows rows4..rows4+5
        const int bU = (((ch * 4 + ks * 2 + kh) * XSTRIDE) + rows4 * 34 + l31) << 3;

        auto dx_group = [&](int g, int pos0) {
            const int gU = g << 3;               // dx offset (u16 units)
            s16x8 B0 = *(const s16x8*)(&xls[bU + gU]);
            s16x8 B1 = *(const s16x8*)(&xls[bU + gU + 1 * (34 << 3)]);
            s16x8 B2 = *(const s16x8*)(&xls[bU + gU + 2 * (34 << 3)]);
            s16x8 B3 = *(const s16x8*)(&xls[bU + gU + 3 * (34 << 3)]);
            s16x8 B4 = *(const s16x8*)(&xls[bU + gU + 4 * (34 << 3)]);
            s16x8 B5 = *(const s16x8*)(&xls[bU + gU + 5 * (34 << 3)]);
            __builtin_amdgcn_s_setprio(1);
#pragma unroll
            for (int dy = 0; dy < 3; ++dy) {
                const int atU = wbU + oA2 + (pos0 + dy) * 1024;
                s16x8 a = *(const s16x8*)(&wls[atU]);          // 32 co (half)
                s16x8 bn0 = (dy == 0) ? B0 : (dy == 1) ? B1 : B2;
                s16x8 bn1 = (dy == 0) ? B1 : (dy == 1) ? B2 : B3;
                s16x8 bn2 = (dy == 0) ? B2 : (dy == 1) ? B3 : B4;
                s16x8 bn3 = (dy == 0) ? B3 : (dy == 1) ? B4 : B5;
                acc0 = __builtin_amdgcn_mfma_f32_32x32x16_bf16(a, bn0, acc0, 0, 0, 0);
                acc1 = __builtin_amdgcn_mfma_f32_32x32x16_bf16(a, bn1, acc1, 0, 0, 0);
                acc2 = __builtin_amdgcn_mfma_f32_32x32x16_bf16(a, bn2, acc2, 0, 0, 0);
                acc3 = __builtin_amdgcn_mfma_f32_32x32x16_bf16(a, bn3, acc3, 0, 0, 0);
            }
            __builtin_amdgcn_s_setprio(0);
        };

        dx_group(0, 0);
        dx_group(1, 3);
        dx_group(2, 6);

        if ((s & 3) == 3) epi(s >> 2);           // expert complete (pure VALU)
    }

    // store NCHW f32: per instr 32 consecutive px x 1 co (128 B segments)
    const int yy = h0 + rows4;
#pragma unroll
    for (int j = 0; j < 16; ++j) {
        const int co = half * 32 + (j & 3) + 8 * (j >> 2) + 4 * kh;
        const long rb = ((long)(b * 64 + co)) * 160;
        out[(rb + yy + 0) * 160 + w0 + l31] = oac0[j];
        out[(rb + yy + 1) * 160 + w0 + l31] = oac1[j];
        out[(rb + yy + 2) * 160 + w0 + l31] = oac2[j];
        out[(rb + yy + 3) * 160 + w0 + l31] = oac3[j];
    }
}

extern "C" void kernel_launch(void* const* d_in, const int* in_sizes, int n_in,
                              void* d_out, int out_size, void* d_ws, size_t ws_size,
                              hipStream_t stream) {
    const float* x = (const float*)d_in[0];
    const float* fc1w = (const float*)d_in[1];
    const float* fc2w = (const float*)d_in[2];
    const float* fc2b = (const float*)d_in[3];
    const float* convw = (const float*)d_in[4];
    const float* gamma = (const float*)d_in[5];
    const float* beta = (const float*)d_in[6];
    const float* mean = (const float*)d_in[7];
    const float* var = (const float*)d_in[8];
    float* out = (float*)d_out;
    char* ws = (char*)d_ws;
    u16* xt = (u16*)(ws + OFF_XT);
    u16* wtb = (u16*)(ws + OFF_WT);
    float* shift = (float*)(ws + OFF_SH);
    float* g = (float*)(ws + OFF_G);
    float* wexp = (float*)(ws + OFF_WE);
    float* gpart = (float*)(ws + OFF_GP);

    hipFuncSetAttribute((const void*)conv_main,
                        hipFuncAttributeMaxDynamicSharedMemorySize, SMEM_TOTAL);

    prep_w<<<576, 256, 0, stream>>>(convw, wtb, gamma, beta, mean, var, shift);
    prep_x<<<15392, 256, 0, stream>>>(x, xt, gpart);
    g_reduce<<<1024, 256, 0, stream>>>(gpart, g);
    router<<<1, 256, 0, stream>>>(g, fc1w, fc2w, fc2b, wexp);
    conv_main<<<1600, 256, SMEM_TOTAL, stream>>>(xt, wtb, shift, wexp, out);
}